// Round 1
// baseline (158.483 us; speedup 1.0000x reference)
//
#include <hip/hip_runtime.h>

// ---------------------------------------------------------------------------
// Loss_17729624998144: bicubic-warp temporal loss.
// out = mean|ex*M1*(warp(in1)-prev)| + mean|msk*ex*(1-M1)*(warp(in2)-warp(fast))|
// where msk = inside-grid AND NOT(4x4-maxpooled occlusion OR 2px border),
// M1 = mask1_0 * msk. msk==0 kills BOTH terms at that pixel, so we early-out.
// ---------------------------------------------------------------------------

__device__ __forceinline__ void cr_weights(float t, float w[4]) {
    // Catmull-Rom weights, algebraically identical to the reference's _cubic
    float t2 = t * t, t3 = t2 * t;
    w[0] = 0.5f * (-t + 2.0f * t2 - t3);
    w[1] = 1.0f + 0.5f * (3.0f * t3 - 5.0f * t2);
    w[2] = 0.5f * (t + 4.0f * t2 - 3.0f * t3);
    w[3] = 0.5f * (t3 - t2);
}

__device__ __forceinline__ float bicubic4(const float* __restrict__ p, int W,
                                          const float wx[4], const float wy[4]) {
    // p points at (y0, x0); taps are 4 consecutive columns in 4 consecutive rows
    float s = 0.0f;
#pragma unroll
    for (int k = 0; k < 4; ++k) {
        const float* r = p + k * W;
        float h = wx[0] * r[0];
        h = fmaf(wx[1], r[1], h);
        h = fmaf(wx[2], r[2], h);
        h = fmaf(wx[3], r[3], h);
        s = fmaf(wy[k], h, s);
    }
    return s;
}

// K1: horizontally-pooled (dx in -1..2) occlusion bitmap; also zero the acc.
__global__ void occl_hpool_kernel(const float* __restrict__ flow,
                                  unsigned char* __restrict__ mh,
                                  double* __restrict__ acc, int H, int W) {
    int idx = blockIdx.x * blockDim.x + threadIdx.x;
    if (idx == 0) acc[0] = 0.0;
    int HW = H * W;
    if (idx >= HW) return;
    int y = idx / W;
    int x = idx - y * W;
    const float* __restrict__ f0 = flow;       // flow[0,0]
    const float* __restrict__ f1 = flow + HW;  // flow[0,1]
    bool have_a = (y < H - 1);
    int m = 0;
#pragma unroll
    for (int dx = -1; dx <= 2; ++dx) {
        int xx = x + dx;
        if (xx < 0 || xx >= W) continue;
        float a = have_a ? (f0[(y + 1) * W + xx] - f0[y * W + xx]) : 0.0f;
        float b = (xx < W - 1) ? (f1[y * W + xx + 1] - f1[y * W + xx]) : 0.0f;
        m |= (fabsf(a + b) > 0.75f) ? 1 : 0;
    }
    mh[idx] = (unsigned char)m;
}

__global__ void zero_acc_kernel(double* __restrict__ acc) { acc[0] = 0.0; }

// K2: main loss kernel. INLINE_OCC=true computes the pooled occlusion from
// flow directly (fallback when ws is too small for the bitmap).
template <bool INLINE_OCC>
__global__ void loss_kernel(const float* __restrict__ in1,
                            const float* __restrict__ in2,
                            const float* __restrict__ prev,
                            const float* __restrict__ flow,
                            const float* __restrict__ m10,
                            const float* __restrict__ ex,
                            const float* __restrict__ fast,
                            const unsigned char* __restrict__ mh,
                            double* __restrict__ acc, int H, int W) {
    int idx = blockIdx.x * blockDim.x + threadIdx.x;
    int HW = H * W;
    float local = 0.0f;
    if (idx < HW) {
        int y = idx / W;
        int x = idx - y * W;
        int occ;
        if (y < 2 || y >= H - 2 || x < 2 || x >= W - 2) {
            occ = 1;  // border rows/cols are forced to mask=1
        } else if (INLINE_OCC) {
            occ = 0;
            const float* __restrict__ f0 = flow;
            const float* __restrict__ f1 = flow + HW;
            // y in [2,H-3], x in [2,W-3] => yy in [1,H-1], xx in [1,W-1]: no OOB
            for (int dy = -1; dy <= 2; ++dy) {
                int yy = y + dy;
                for (int dx = -1; dx <= 2; ++dx) {
                    int xx = x + dx;
                    float a = (yy < H - 1) ? (f0[(yy + 1) * W + xx] - f0[yy * W + xx]) : 0.0f;
                    float b = (xx < W - 1) ? (f1[yy * W + xx + 1] - f1[yy * W + xx]) : 0.0f;
                    occ |= (fabsf(a + b) > 0.75f) ? 1 : 0;
                }
            }
        } else {
            occ = 0;
#pragma unroll
            for (int dy = -1; dy <= 2; ++dy) occ |= mh[(y + dy) * W + x];
        }

        if (!occ) {  // rare path: pixel survives the occlusion+border mask
            float fx = flow[idx];
            float fy = flow[HW + idx];
            float gx = (float)x + fx;
            float gy = (float)y + fy;
            float fgx = floorf(gx), fgy = floorf(gy);
            int x0 = (int)fgx - 1;  // == floor(gx-1), exact
            int y0 = (int)fgy - 1;
            if (x0 >= 0 && x0 <= W - 4 && y0 >= 0 && y0 <= H - 4) {  // inside
                float tx = gx - fgx, ty = gy - fgy;
                float wx[4], wy[4];
                cr_weights(tx, wx);
                cr_weights(ty, wy);
                size_t base = (size_t)y0 * W + x0;
#pragma unroll
                for (int c = 0; c < 3; ++c) {
                    size_t coff = (size_t)c * HW;
                    float w1 = bicubic4(in1 + coff + base, W, wx, wy);
                    float w2 = bicubic4(in2 + coff + base, W, wx, wy);
                    float wf = bicubic4(fast + coff + base, W, wx, wy);
                    float M = m10[coff + idx];  // msk==1 here
                    float e = ex[coff + idx];
                    float t1 = fabsf(e * M * (w1 - prev[coff + idx]));
                    float t2 = fabsf(e * (1.0f - M) * (w2 - wf));
                    local += t1 + t2;
                }
            }
        }
    }

    // block reduction (wave64 shuffle + LDS across the 4 waves)
#pragma unroll
    for (int off = 32; off > 0; off >>= 1) local += __shfl_down(local, off, 64);
    __shared__ float wsum[4];
    int wid = threadIdx.x >> 6;
    if ((threadIdx.x & 63) == 0) wsum[wid] = local;
    __syncthreads();
    if (threadIdx.x == 0) {
        float s = wsum[0] + wsum[1] + wsum[2] + wsum[3];
        if (s != 0.0f) atomicAdd(acc, (double)s);
    }
}

__global__ void finalize_kernel(const double* __restrict__ acc,
                                float* __restrict__ out, double invN) {
    out[0] = (float)(acc[0] * invN);
}

extern "C" void kernel_launch(void* const* d_in, const int* in_sizes, int n_in,
                              void* d_out, int out_size, void* d_ws, size_t ws_size,
                              hipStream_t stream) {
    const float* in1  = (const float*)d_in[0];  // input1  (1,3,H,W)
    const float* in2  = (const float*)d_in[1];  // input2  (1,3,H,W)
    const float* prev = (const float*)d_in[2];  // prev_frame1 (3,H,W)
    const float* flow = (const float*)d_in[3];  // flow1   (1,2,H,W)
    const float* m10  = (const float*)d_in[4];  // mask1_0 (1,3,H,W)
    const float* ex   = (const float*)d_in[5];  // exclusive_mask1 (1,3,H,W)
    const float* fast = (const float*)d_in[6];  // fastdvdnet (1,3,H,W)
    float* out = (float*)d_out;

    const int H = 1080, W = 1920;
    const int HW = H * W;

    double* acc = (double*)d_ws;
    unsigned char* mh = (unsigned char*)d_ws + 64;

    const int threads = 256;
    const int blocks = (HW + threads - 1) / threads;
    const double invN = 1.0 / (3.0 * (double)HW);  // both means over B*C*H*W

    if (ws_size >= (size_t)HW + 64) {
        occl_hpool_kernel<<<blocks, threads, 0, stream>>>(flow, mh, acc, H, W);
        loss_kernel<false><<<blocks, threads, 0, stream>>>(in1, in2, prev, flow,
                                                           m10, ex, fast, mh, acc, H, W);
    } else {
        zero_acc_kernel<<<1, 1, 0, stream>>>(acc);
        loss_kernel<true><<<blocks, threads, 0, stream>>>(in1, in2, prev, flow,
                                                          m10, ex, fast, nullptr, acc, H, W);
    }
    finalize_kernel<<<1, 1, 0, stream>>>(acc, out, invN);
}